// Round 2
// baseline (207.047 us; speedup 1.0000x reference)
//
#include <hip/hip_runtime.h>

// SGE-style gate: B=64, C=512, HW=784, G=8, cpg=64. One block per (b,g).
//
// R5: abandon register-residency of the 200KB tile (R2-R4 evidence: compiler
// parks it in AGPRs, VGPR=128+AGPR~128 -> 1 block/CU, load phase staged
// through accvgpr writes, stuck at 2.4TB/s). Instead: 3 passes over the tile,
// re-reads served by L2/L3 (x=103MB + out=103MB < 256MB Infinity Cache).
//   A: row-strip read (HBM cold) -> per-channel mean (8 thr/channel shuffle)
//   B: column read (LLC hit)     -> s[p] = sum_c x[c,p]*mean_c, in-register
//   C: mu/var block-reduce -> gate[784] in LDS
//   D: row-strip re-read (LLC)   -> out = x * gate (HBM write)
// 512 threads, VGPR ~64, LDS 3.5KB -> 2 blocks/CU co-resident, 16 waves/CU,
// every phase a deep-MLP coalesced stream.
//
// Thread map (phases A/D): t = c*8 + jj; thread owns float4 idx jj+8k
// (k=0..23) + tail idx 192+jj for jj<4 (196 float4/row).
// Phase B: thread owns positions p0=t, p1=t+512 (p1 valid for t<272).

#define HW    784
#define HW4   196
#define CPG   64
#define NG    8

__global__ __launch_bounds__(512, 4)
void sge_kernel(const float* __restrict__ x,
                const float* __restrict__ weight,
                const float* __restrict__ bias,
                float* __restrict__ out) {
    __shared__ float means[CPG];
    __shared__ float gate[HW];
    __shared__ float red[16];

    const int t    = threadIdx.x;     // 0..511
    const int lane = t & 63;
    const int wave = t >> 6;          // 0..7
    const int c    = t >> 3;          // 0..63 channel
    const int jj   = t & 7;           // strip phase within channel

    const int bg = blockIdx.x;        // b*8 + g
    const int g  = bg & (NG - 1);
    const size_t tile4 = (size_t)bg * (CPG * HW4);
    const float4* xp = (const float4*)x + tile4 + (size_t)c * HW4;

    // ---- Phase A: per-channel spatial mean (row strips, 8 threads/channel) ----
    float cs = 0.f;
#pragma unroll
    for (int k = 0; k < 24; ++k) {
        const float4 v = xp[jj + 8 * k];
        cs += (v.x + v.y) + (v.z + v.w);
    }
    if (jj < 4) {
        const float4 v = xp[192 + jj];
        cs += (v.x + v.y) + (v.z + v.w);
    }
    cs += __shfl_xor(cs, 1, 64);
    cs += __shfl_xor(cs, 2, 64);
    cs += __shfl_xor(cs, 4, 64);
    if (jj == 0) means[c] = cs * (1.0f / (float)HW);
    __syncthreads();

    // ---- Phase B: s[p] = sum_c x[c,p]*mean_c (column reads, LLC-hit) ----
    const float* xs = x + (size_t)bg * (CPG * HW);
    const bool  has1 = (t + 512) < HW;            // t < 272
    const int   p1   = has1 ? (t + 512) : t;      // clamped (dup read, L1 hit)
    float s0 = 0.f, s1 = 0.f;
#pragma unroll 8
    for (int cc = 0; cc < CPG; ++cc) {
        const float  mc   = means[cc];
        const float* rowp = xs + (size_t)cc * HW;
        s0 += rowp[t]  * mc;
        s1 += rowp[p1] * mc;
    }

    // ---- Phase C: mu/var block-reduce, gate into LDS ----
    float rs  = s0 + (has1 ? s1 : 0.f);
    float rs2 = s0 * s0 + (has1 ? s1 * s1 : 0.f);
#pragma unroll
    for (int m = 1; m < 64; m <<= 1) {
        rs  += __shfl_xor(rs,  m, 64);
        rs2 += __shfl_xor(rs2, m, 64);
    }
    if (lane == 0) { red[wave] = rs; red[8 + wave] = rs2; }
    __syncthreads();

    float sum_s = 0.f, sum_s2 = 0.f;
#pragma unroll
    for (int w = 0; w < 8; ++w) { sum_s += red[w]; sum_s2 += red[8 + w]; }
    const float mu   = sum_s * (1.0f / (float)HW);
    const float var  = sum_s2 * (1.0f / (float)HW) - mu * mu;
    const float rstd = rsqrtf(var + 1e-5f);
    const float wg   = weight[g];
    const float bgv  = bias[g];

    {
        const float z0 = (s0 - mu) * rstd * wg + bgv;
        gate[t] = 1.0f / (1.0f + __expf(-z0));
        if (has1) {
            const float z1 = (s1 - mu) * rstd * wg + bgv;
            gate[t + 512] = 1.0f / (1.0f + __expf(-z1));
        }
    }
    __syncthreads();

    // ---- Phase D: out = x * gate (row strips re-read from LLC) ----
    const float4* g4 = (const float4*)gate;
    float4* op = (float4*)out + tile4 + (size_t)c * HW4;
#pragma unroll
    for (int k = 0; k < 24; ++k) {
        const float4 v  = xp[jj + 8 * k];
        const float4 gv = g4[jj + 8 * k];
        float4 o;
        o.x = v.x * gv.x; o.y = v.y * gv.y;
        o.z = v.z * gv.z; o.w = v.w * gv.w;
        op[jj + 8 * k] = o;
    }
    if (jj < 4) {
        const float4 v  = xp[192 + jj];
        const float4 gv = g4[192 + jj];
        float4 o;
        o.x = v.x * gv.x; o.y = v.y * gv.y;
        o.z = v.z * gv.z; o.w = v.w * gv.w;
        op[192 + jj] = o;
    }
}

extern "C" void kernel_launch(void* const* d_in, const int* in_sizes, int n_in,
                              void* d_out, int out_size, void* d_ws, size_t ws_size,
                              hipStream_t stream) {
    const float* x      = (const float*)d_in[0];
    const float* weight = (const float*)d_in[1];
    const float* bias   = (const float*)d_in[2];
    float* out = (float*)d_out;
    sge_kernel<<<dim3(512), dim3(512), 0, stream>>>(x, weight, bias, out);
}